// Round 5
// baseline (186.368 us; speedup 1.0000x reference)
//
#include <hip/hip_runtime.h>
#include <hip/hip_bf16.h>

// Problem: B=8, N=2048, M=1024, C=512, H=8, D=64
// Pipeline (3 launches):
//   1) prep (192 blocks): weights -> bf16 W' chunked frag layout only.
//   2) proj GEMM: W DMA'd (global_load_lds, ring-2); A (x/gt f32) fused:
//      coalesced float4 loads (8 rows/inst) -> in-reg cvt -> ds_write_b64
//      into the same bf16 frag-chunk layout. 1 __syncthreads per k-iter
//      (R3's proven skeleton). XCD-chunked block swizzle for A-panel L2 reuse.
//      Epilogue: Q/K via wave-private swizzled LDS -> coalesced 1KB stores;
//      V direct b64 stores.
//   3) flash attention: ring-4 subtile buffers, counted vmcnt + raw barriers.

typedef __bf16 bf16_t;
typedef __bf16 bf16x8 __attribute__((ext_vector_type(8)));
typedef __bf16 bf16x4 __attribute__((ext_vector_type(4)));
typedef float floatx16 __attribute__((ext_vector_type(16)));
typedef unsigned int uintx4 __attribute__((ext_vector_type(4)));
typedef unsigned int uintx2 __attribute__((ext_vector_type(2)));

#define KDIM 512
#define QSCALE 1.44269504088896f

#define WAITVM(N) asm volatile("s_waitcnt vmcnt(" #N ")" ::: "memory")
#define BAR()                                  \
  do {                                         \
    __builtin_amdgcn_s_barrier();              \
    asm volatile("" ::: "memory");             \
  } while (0)

__device__ __forceinline__ unsigned pack2(float a, float b) {
  unsigned short ua = __builtin_bit_cast(unsigned short, (bf16_t)a);
  unsigned short ub = __builtin_bit_cast(unsigned short, (bf16_t)b);
  return (unsigned)ua | ((unsigned)ub << 16);
}

__device__ __forceinline__ float fexp2(float x) {
#if __has_builtin(__builtin_amdgcn_exp2f)
  return __builtin_amdgcn_exp2f(x);
#else
  return __exp2f(x);
#endif
}

__device__ __forceinline__ bf16x8 cvt8(const float4 a, const float4 b) {
  bf16x8 r;
  r[0] = (bf16_t)a.x; r[1] = (bf16_t)a.y; r[2] = (bf16_t)a.z; r[3] = (bf16_t)a.w;
  r[4] = (bf16_t)b.x; r[5] = (bf16_t)b.y; r[6] = (bf16_t)b.z; r[7] = (bf16_t)b.w;
  return r;
}

__device__ __forceinline__ bf16x4 cvt4(const float4 a) {
  bf16x4 r;
  r[0] = (bf16_t)a.x; r[1] = (bf16_t)a.y; r[2] = (bf16_t)a.z; r[3] = (bf16_t)a.w;
  return r;
}

// 16B-per-lane global->LDS DMA (dest = wave-uniform base + lane*16).
__device__ __forceinline__ void gl_lds16(const bf16_t* g, bf16_t* l) {
#if __has_builtin(__builtin_amdgcn_global_load_lds)
  __builtin_amdgcn_global_load_lds(
      (const __attribute__((address_space(1))) unsigned int*)(g),
      (__attribute__((address_space(3))) unsigned int*)(l), 16, 0, 0);
#else
  *(bf16x8*)l = *(const bf16x8*)g;
#endif
}

// ---------------- prep: weight transpose only (192 blocks) ----------------
// blocks 0..63: Wq transpose; 64..191: Wkv transpose.
// Chunk layout per 128(col) x 32(k) tile (8KB): 8 chunks of 512 elems;
// elem(c,k): chunk=((c&127)>>5)*2+((k&31)>>4), off=(c&31)*8+((k>>3)&1)*256+(k&7)
__global__ __launch_bounds__(256) void prep_kernel(
    const float* __restrict__ Wq, const float* __restrict__ Wkv,
    bf16_t* __restrict__ Wqt, bf16_t* __restrict__ Wkvt) {
  __shared__ float tile[64][65];
  const int blk = blockIdx.x;
  const int t = threadIdx.x;
  const float* in; bf16_t* out; int N, bx, by;
  if (blk < 64) { in = Wq; out = Wqt; N = 512; bx = blk & 7; by = blk >> 3; }
  else { int t2 = blk - 64; in = Wkv; out = Wkvt; N = 1024; bx = t2 & 15; by = t2 >> 4; }
  const int c0 = bx * 64, k0 = by * 64;
#pragma unroll
  for (int i = 0; i < 16; ++i) {
    int idx = t + i * 256;
    int kk = idx >> 6, cc = idx & 63;
    tile[kk][cc] = in[(size_t)(k0 + kk) * N + (c0 + cc)];
  }
  __syncthreads();
#pragma unroll
  for (int j = 0; j < 2; ++j) {
    int unit = t + j * 256;
    int cc = unit >> 3, ks = (unit & 7) * 8;
    int c = c0 + cc, k = k0 + ks;
    bf16x8 v;
#pragma unroll
    for (int i = 0; i < 8; ++i) v[i] = (bf16_t)tile[ks + i][cc];
    const int k5 = k & 31;
    const int chunk = ((c & 127) >> 5) * 2 + (k5 >> 4);
    *(bf16x8*)(&out[(size_t)((c >> 7) * 16 + (k >> 5)) * 4096 + chunk * 512 +
                    (c & 31) * 8 + ((k5 >> 3) & 1) * 256]) = v;
  }
}

// ---------------- projection GEMM (128x128 tile, BK=32, fused A-cvt) -------------
// logical blocks 0..511: Q (x[16384,512]); 512..1023: KV (gt[8192,512]).
// XCD-chunked swizzle: A-panel sharers (consecutive logical ids) -> same XCD.
// 4 waves 2x2; wave computes 64x64 (2x2 mfma_32x32x16).
// A: wave w loads rows [32w..32w+32) of the 128x32 f32 tile with 4 coalesced
//    float4 insts (8 rows x 128B each), cvt -> 4x ds_write_b64 into frag layout.
// W: global_load_lds DMA (2 segs/wave). Ring-2 LDS, 1 barrier/iter.
__global__ __launch_bounds__(256) void proj_gemm_kernel(
    const float* __restrict__ x, const float* __restrict__ gt,
    const bf16_t* __restrict__ Wqt, const bf16_t* __restrict__ Wkvt,
    const float* __restrict__ bq, const float* __restrict__ bkv,
    bf16_t* __restrict__ Qf, bf16_t* __restrict__ Kf, bf16_t* __restrict__ Vf) {
  __shared__ bf16_t lds[2][8192];  // [buf][ A 4096 | W 4096 ] = 32KB
  const int raw = blockIdx.x;
  const int blk = (raw & 7) * 128 + (raw >> 3);
  int mode, bx, by;
  const float* Asrc; const bf16_t* Wb; const float* bias;
  if (blk < 512) { mode = 0; bx = blk & 3; by = blk >> 2; Asrc = x; Wb = Wqt; bias = bq; }
  else { int tt = blk - 512; mode = 1; bx = tt & 7; by = tt >> 3; Asrc = gt; Wb = Wkvt; bias = bkv; }

  const int tid = threadIdx.x;
  const int wave = tid >> 6, L = tid & 63;
  const int l5 = L & 31, hf = L >> 5;
  const int wr = wave >> 1, wc = wave & 1;
  const int rb = by * 128, cb = bx * 128;

  // ---- A fused staging ----
  // inst j (0..3): lane L -> row rb + 32*wave + 8j + (L>>3), f32x4 unit u = L&7
  const float* abase = Asrc + (size_t)(rb + 32 * wave + (L >> 3)) * KDIM + (L & 7) * 4;
  const int u = L & 7;
  // LDS elem offset (per j): chunk = wave*2 + (u>>2); within = (8j+(L>>3))*8
  //   + ((u>>1)&1)*256 + (u&1)*4   [matches frag elem(row,k) mapping]
  const int aoff0 = (wave * 2 + (u >> 2)) * 512 + (L >> 3) * 8 +
                    ((u >> 1) & 1) * 256 + (u & 1) * 4;

  float4 av[4];
  auto loadA = [&](int kt) {
#pragma unroll
    for (int j = 0; j < 4; ++j)
      av[j] = *(const float4*)(abase + (size_t)(8 * j) * KDIM + kt * 32);
  };
  auto writeA = [&](int buf) {
#pragma unroll
    for (int j = 0; j < 4; ++j)
      *(bf16x4*)(&lds[buf][aoff0 + j * 64]) = cvt4(av[j]);
  };

  const bf16_t* Wbase = Wb + (size_t)bx * 16 * 4096 + L * 8;
  auto dmaW = [&](int buf, int kt) {
#pragma unroll
    for (int j = 0; j < 2; ++j) {
      const int s = wave * 2 + j;
      gl_lds16(Wbase + (size_t)kt * 4096 + s * 512, &lds[buf][4096 + s * 512 + L * 8]);
    }
  };

  loadA(0);
  dmaW(0, 0);
  writeA(0);
  __syncthreads();  // k-tile 0 landed (A writes + W DMA drained)

  floatx16 acc[2][2] = {};
  for (int kt = 0; kt < 16; ++kt) {
    const int cur = kt & 1;
    if (kt < 15) {
      loadA(kt + 1);        // coalesced f32 -> reg; consumed after MFMAs
      dmaW(cur ^ 1, kt + 1);
    }
    bf16x8 af[2][2], wf[2][2];
#pragma unroll
    for (int rs = 0; rs < 2; ++rs)
#pragma unroll
      for (int kh = 0; kh < 2; ++kh)
        af[rs][kh] = *(const bf16x8*)(&lds[cur][((wr * 2 + rs) * 2 + kh) * 512 + L * 8]);
#pragma unroll
    for (int cs = 0; cs < 2; ++cs)
#pragma unroll
      for (int kh = 0; kh < 2; ++kh)
        wf[cs][kh] = *(const bf16x8*)(&lds[cur][4096 + ((wc * 2 + cs) * 2 + kh) * 512 + L * 8]);
    __builtin_amdgcn_s_setprio(1);
#pragma unroll
    for (int rs = 0; rs < 2; ++rs)
#pragma unroll
      for (int cs = 0; cs < 2; ++cs)
#pragma unroll
        for (int kh = 0; kh < 2; ++kh)
          acc[rs][cs] = __builtin_amdgcn_mfma_f32_32x32x16_bf16(
              af[rs][kh], wf[cs][kh], acc[rs][cs], 0, 0, 0);
    __builtin_amdgcn_s_setprio(0);
    if (kt < 15) writeA(cur ^ 1);  // cvt waits f32 loads; hidden by MFMAs
    __syncthreads();  // drains W DMA + everyone's reads/writes of cur
  }

  // ---------------- epilogue ----------------
  // C/D layout: col=lane&31, row=(r&3)+8*(r>>2)+4*(lane>>5).
  // Q and K: stage wave's 64x64 bf16 tile in private 8KB LDS in exact Qf/Kf
  // byte order with XOR swizzle q^=((q>>9)&7)<<4, then 8 coalesced 1KB stores.
  const int colb = cb + wc * 64;  // 64-aligned wave col base
  char* stc = (char*)(&lds[0][0] + wave * 4096);  // wave-private 8KB
  const int gr0 = rb + wr * 64;

  if (mode == 0 || colb < 512) {
    bf16_t* dstT; size_t base2;
    const int hh = (colb & 511) >> 6;
    if (mode == 0) {
      const int b = gr0 >> 11, n0 = gr0 & 2047;
      base2 = 2 * ((size_t)(b * 8 + hh) * 131072 + (size_t)(n0 >> 5) * 2048);
      dstT = Qf;
    } else {
      const int b = gr0 >> 10, m0 = gr0 & 1023;
      base2 = 2 * ((size_t)(b * 8 + hh) * 65536 + (size_t)(m0 >> 5) * 2048);
      dstT = Kf;
    }
#pragma unroll
    for (int rs = 0; rs < 2; ++rs)
#pragma unroll
      for (int cs = 0; cs < 2; ++cs) {
        const int d = cs * 32 + l5;
        const float bv = bias[colb + cs * 32 + l5];
#pragma unroll
        for (int r = 0; r < 16; ++r) {
          const int nl = rs * 32 + (r & 3) + 8 * (r >> 2) + 4 * hf;
          float v = acc[rs][cs][r] + bv;
          if (mode == 0) v *= QSCALE;
          int q = ((nl >> 5) << 12) | ((d >> 3) << 9) | ((nl & 31) << 4) | ((d & 7) << 1);
          q ^= ((q >> 9) & 7) << 4;
          *(bf16_t*)(stc + q) = (bf16_t)v;
        }
      }
    // wave-private region: within-wave ds ordering handled by compiler lgkmcnt
#pragma unroll
    for (int g = 0; g < 8; ++g) {
      const int q = g * 1024 + L * 16;
      const int qs = q ^ (((q >> 9) & 7) << 4);
      bf16x8 vv = *(const bf16x8*)(stc + qs);
      *(bf16x8*)((char*)dstT + base2 + q) = vv;
    }
  } else {  // V waves: direct b64 frag stores
#pragma unroll
    for (int rs = 0; rs < 2; ++rs)
#pragma unroll
      for (int cs = 0; cs < 2; ++cs) {
        const int col = colb + cs * 32 + l5;
        const float bv = bias[col];
        const int grb = gr0 + rs * 32;
        const int cc = col - 512;
        const int hh = cc >> 6, d = cc & 63;
        const int dof = (d >> 5) * 1024 + (d & 31) * 8;
#pragma unroll
        for (int rq = 0; rq < 4; ++rq) {
          int gr = grb + 8 * rq + 4 * hf;
          int b = gr >> 10, m = gr & 1023;
          bf16x4 pk;
          pk[0] = (bf16_t)(acc[rs][cs][rq * 4 + 0] + bv);
          pk[1] = (bf16_t)(acc[rs][cs][rq * 4 + 1] + bv);
          pk[2] = (bf16_t)(acc[rs][cs][rq * 4 + 2] + bv);
          pk[3] = (bf16_t)(acc[rs][cs][rq * 4 + 3] + bv);
          *(bf16x4*)(&Vf[(size_t)(b * 8 + hh) * 65536 + (m >> 5) * 2048 + dof +
                         ((m >> 4) & 1) * 512 + ((m >> 3) & 1) * 256 + (m & 7)]) = pk;
        }
      }
  }
}

// ---------------- flash attention (ring-4 subtile pipeline) ----------------
__global__ __launch_bounds__(256, 4) void flash_attn_kernel(
    const bf16_t* __restrict__ Qf, const bf16_t* __restrict__ Kf,
    const bf16_t* __restrict__ Vf, float* __restrict__ out) {
  __shared__ bf16_t kv[4][4096];  // 32KB total
  const int tid = threadIdx.x;
  const int wave = tid >> 6, L = tid & 63;
  const int l5 = L & 31, hf = L >> 5;
  const int bh = blockIdx.y;
  const int b = bh >> 3, hh = bh & 7;
  const int nb = blockIdx.x * 128 + wave * 32;

  const bf16_t* Qp = Qf + (size_t)bh * 131072 + (nb >> 5) * 2048 + L * 8;
  const bf16_t* Kb = Kf + (size_t)bh * 65536 + L * 8;
  const bf16_t* Vb = Vf + (size_t)bh * 65536 + L * 8;

  bf16x8 qf[4];
#pragma unroll
  for (int kc = 0; kc < 4; ++kc) qf[kc] = *(const bf16x8*)(Qp + kc * 512);

  bf16x8 ones;
#pragma unroll
  for (int i = 0; i < 8; ++i) ones[i] = (bf16_t)1.0f;

  floatx16 o0 = {}, o1 = {}, lacc = {};

  auto dma = [&](int buf, int s) {
#pragma unroll
    for (int j = 0; j < 2; ++j) {
      const int q = wave * 2 + j;
      const bf16_t* g = (q < 4) ? (Kb + (size_t)s * 2048 + q * 512)
                                : (Vb + (size_t)s * 2048 + (q - 4) * 512);
      gl_lds16(g, &kv[buf][(q < 4 ? q * 512 : 2048 + (q - 4) * 512) + L * 8]);
    }
  };

  auto subtile = [&](int s) {
    const bf16_t* kb = &kv[s & 3][L * 8];
    const bf16_t* vb = &kv[s & 3][2048 + L * 8];
    bf16x8 kf4[4];
#pragma unroll
    for (int kc = 0; kc < 4; ++kc) kf4[kc] = *(const bf16x8*)(kb + kc * 512);
    floatx16 sa = {};
    __builtin_amdgcn_s_setprio(1);
#pragma unroll
    for (int kc = 0; kc < 4; ++kc)
      sa = __builtin_amdgcn_mfma_f32_32x32x16_bf16(kf4[kc], qf[kc], sa, 0, 0, 0);
    __builtin_amdgcn_s_setprio(0);
    bf16x8 vf4[4];
#pragma unroll
    for (int j = 0; j < 4; ++j) vf4[j] = *(const bf16x8*)(vb + j * 512);
    unsigned w[8];
#pragma unroll
    for (int i = 0; i < 8; ++i) {
      float pa = fexp2(sa[2 * i]), pb = fexp2(sa[2 * i + 1]);
      w[i] = pack2(pa, pb);
    }
    uintx4 fw0, fw1;
#if __has_builtin(__builtin_amdgcn_permlane32_swap)
    {
      uintx2 r0 = __builtin_amdgcn_permlane32_swap(w[0], w[2], false, false);
      uintx2 r1 = __builtin_amdgcn_permlane32_swap(w[1], w[3], false, false);
      uintx2 r2 = __builtin_amdgcn_permlane32_swap(w[4], w[6], false, false);
      uintx2 r3 = __builtin_amdgcn_permlane32_swap(w[5], w[7], false, false);
      fw0.x = r0[0]; fw0.z = r0[1];
      fw0.y = r1[0]; fw0.w = r1[1];
      fw1.x = r2[0]; fw1.z = r2[1];
      fw1.y = r3[0]; fw1.w = r3[1];
    }
#else
    {
      unsigned sw[8];
#pragma unroll
      for (int i = 0; i < 8; ++i) sw[i] = __shfl_xor(w[i], 32);
      fw0.x = hf ? sw[2] : w[0]; fw0.y = hf ? sw[3] : w[1];
      fw0.z = hf ? w[2] : sw[0]; fw0.w = hf ? w[3] : sw[1];
      fw1.x = hf ? sw[6] : w[4]; fw1.y = hf ? sw[7] : w[5];
      fw1.z = hf ? w[6] : sw[4]; fw1.w = hf ? w[7] : sw[5];
    }
#endif
    bf16x8 pf0 = __builtin_bit_cast(bf16x8, fw0);
    bf16x8 pf1 = __builtin_bit_cast(bf16x8, fw1);
    __builtin_amdgcn_s_setprio(1);
    lacc = __builtin_amdgcn_mfma_f32_32x32x16_bf16(ones, pf0, lacc, 0, 0, 0);
    lacc = __builtin_amdgcn_mfma_f32_32x32x16_bf16(ones, pf1, lacc, 0, 0, 0);
    o0 = __builtin_amdgcn_mfma_f32_32x32x16_bf16(vf4[0], pf0, o0, 0, 0, 0);
    o0 = __builtin_amdgcn_mfma_f32_32x32x16_bf16(vf4[1], pf1, o0, 0, 0, 0);
    o1 = __builtin_amdgcn_mfma_f32_32x32x16_bf16(vf4[2], pf0, o1, 0, 0, 0);
    o1 = __builtin_amdgcn_mfma_f32_32x32x16_bf16(vf4[3], pf1, o1, 0, 0, 0);
    __builtin_amdgcn_s_setprio(0);
  };

  dma(0, 0);
  dma(1, 1);
  dma(2, 2);  // 6 loads/wave in flight

  for (int s = 0; s < 30; ++s) {
    WAITVM(4);  // subtile s landed; s+1, s+2 stay in flight
    BAR();
    if (s <= 28) dma((s + 3) & 3, s + 3);
    subtile(s);
  }
  WAITVM(2);
  BAR();
  subtile(30);
  WAITVM(0);
  BAR();
  subtile(31);

  __syncthreads();  // all compute done before LDS is reused for output staging

  const float inv = 1.0f / lacc[0];

  float* lob = (float*)(&kv[0][0]) + wave * (32 * 36);
  const size_t orow = (size_t)b * 2048 + nb;
#pragma unroll
  for (int pass = 0; pass < 2; ++pass) {
    const floatx16& oo = pass ? o1 : o0;
#pragma unroll
    for (int i = 0; i < 8; ++i) {
      const int d = 2 * (i & 1) + 8 * (i >> 1) + 4 * hf;
      float2 a;
      a.x = oo[2 * i] * inv; a.y = oo[2 * i + 1] * inv;
      *(float2*)(&lob[l5 * 36 + d]) = a;
    }
#pragma unroll
    for (int j = 0; j < 4; ++j) {
      int chunk = j * 64 + L;
      int n = chunk >> 3, c = chunk & 7;
      float4 v = *(const float4*)(&lob[n * 36 + c * 4]);
      *(float4*)(&out[(orow + n) * 512 + hh * 64 + pass * 32 + c * 4]) = v;
    }
  }
}

extern "C" void kernel_launch(void* const* d_in, const int* in_sizes, int n_in,
                              void* d_out, int out_size, void* d_ws, size_t ws_size,
                              hipStream_t stream) {
  (void)in_sizes; (void)n_in; (void)out_size; (void)ws_size;
  const float* x   = (const float*)d_in[0];
  const float* gt  = (const float*)d_in[1];
  const float* Wq  = (const float*)d_in[2];
  const float* bq  = (const float*)d_in[3];
  const float* Wkv = (const float*)d_in[4];
  const float* bkv = (const float*)d_in[5];
  float* out = (float*)d_out;

  // ws: weights + Q/K/V frag buffers
  bf16_t* Wqt  = (bf16_t*)d_ws;
  bf16_t* Wkvt = Wqt + (size_t)512 * 512;
  bf16_t* Qf   = Wkvt + (size_t)1024 * 512;
  bf16_t* Kf   = Qf + (size_t)64 * 2048 * 64;
  bf16_t* Vf   = Kf + (size_t)64 * 1024 * 64;

  prep_kernel<<<192, 256, 0, stream>>>(Wq, Wkv, Wqt, Wkvt);
  proj_gemm_kernel<<<1024, 256, 0, stream>>>(x, gt, Wqt, Wkvt, bq, bkv, Qf, Kf, Vf);
  flash_attn_kernel<<<dim3(16, 64), 256, 0, stream>>>(Qf, Kf, Vf, out);
}

// Round 6
// 174.150 us; speedup vs baseline: 1.0702x; 1.0702x over previous
//
#include <hip/hip_runtime.h>
#include <hip/hip_bf16.h>

// Problem: B=8, N=2048, M=1024, C=512, H=8, D=64
// Pipeline (3 launches) — R3 structure (best: 174.8us) + flash XCD-locality:
//   1) prep: (a) weights -> bf16 W' chunked frag layout; (b) x,gt -> bf16 A'
//      chunked frag layout (A' scratch lives in d_out, consumed by proj).
//   2) proj GEMM: both operands DMA'd (global_load_lds), ring-2 LDS, 1 barrier
//      per k-iter; XCD-chunked block swizzle for A'-panel L2 reuse.
//      Epilogue: Q/K staged through wave-private swizzled LDS -> 1KB stores;
//      V direct b64 stores.
//   3) flash attention: ring-4 subtile pipeline; NEW: 1-D grid with XCD-owned
//      bh groups (all 16 n-blocks of one bh on one XCD -> K/V fetched once).

typedef __bf16 bf16_t;
typedef __bf16 bf16x8 __attribute__((ext_vector_type(8)));
typedef __bf16 bf16x4 __attribute__((ext_vector_type(4)));
typedef float floatx16 __attribute__((ext_vector_type(16)));
typedef unsigned int uintx4 __attribute__((ext_vector_type(4)));
typedef unsigned int uintx2 __attribute__((ext_vector_type(2)));

#define KDIM 512
#define QSCALE 1.44269504088896f

#define WAITVM(N) asm volatile("s_waitcnt vmcnt(" #N ")" ::: "memory")
#define BAR()                                  \
  do {                                         \
    __builtin_amdgcn_s_barrier();              \
    asm volatile("" ::: "memory");             \
  } while (0)

__device__ __forceinline__ unsigned pack2(float a, float b) {
  unsigned short ua = __builtin_bit_cast(unsigned short, (bf16_t)a);
  unsigned short ub = __builtin_bit_cast(unsigned short, (bf16_t)b);
  return (unsigned)ua | ((unsigned)ub << 16);
}

__device__ __forceinline__ float fexp2(float x) {
#if __has_builtin(__builtin_amdgcn_exp2f)
  return __builtin_amdgcn_exp2f(x);
#else
  return __exp2f(x);
#endif
}

__device__ __forceinline__ bf16x8 cvt8(const float4 a, const float4 b) {
  bf16x8 r;
  r[0] = (bf16_t)a.x; r[1] = (bf16_t)a.y; r[2] = (bf16_t)a.z; r[3] = (bf16_t)a.w;
  r[4] = (bf16_t)b.x; r[5] = (bf16_t)b.y; r[6] = (bf16_t)b.z; r[7] = (bf16_t)b.w;
  return r;
}

// 16B-per-lane global->LDS DMA (dest = wave-uniform base + lane*16).
__device__ __forceinline__ void gl_lds16(const bf16_t* g, bf16_t* l) {
#if __has_builtin(__builtin_amdgcn_global_load_lds)
  __builtin_amdgcn_global_load_lds(
      (const __attribute__((address_space(1))) unsigned int*)(g),
      (__attribute__((address_space(3))) unsigned int*)(l), 16, 0, 0);
#else
  *(bf16x8*)l = *(const bf16x8*)g;
#endif
}

// ---------------- prep: weight transpose + x/gt convert, chunked frag layouts ----------
// blocks 0..63: Wq transpose; 64..191: Wkv transpose;
// blocks 192..2239: x cvt (128x16 tiles); 2240..3263: gt cvt (64x16 tiles)
__global__ __launch_bounds__(256) void prep_kernel(
    const float* __restrict__ Wq, const float* __restrict__ Wkv,
    const float* __restrict__ x, const float* __restrict__ gt,
    bf16_t* __restrict__ Wqt, bf16_t* __restrict__ Wkvt,
    bf16_t* __restrict__ Aq, bf16_t* __restrict__ Akv) {
  __shared__ float tile[64][65];
  const int blk = blockIdx.x;
  const int t = threadIdx.x;
  if (blk < 192) {
    const float* in; bf16_t* out; int N, bx, by;
    if (blk < 64) { in = Wq; out = Wqt; N = 512; bx = blk & 7; by = blk >> 3; }
    else { int t2 = blk - 64; in = Wkv; out = Wkvt; N = 1024; bx = t2 & 15; by = t2 >> 4; }
    const int c0 = bx * 64, k0 = by * 64;
#pragma unroll
    for (int i = 0; i < 16; ++i) {
      int idx = t + i * 256;
      int kk = idx >> 6, cc = idx & 63;
      tile[kk][cc] = in[(size_t)(k0 + kk) * N + (c0 + cc)];
    }
    __syncthreads();
#pragma unroll
    for (int j = 0; j < 2; ++j) {
      int unit = t + j * 256;
      int cc = unit >> 3, ks = (unit & 7) * 8;
      int c = c0 + cc, k = k0 + ks;
      bf16x8 v;
#pragma unroll
      for (int i = 0; i < 8; ++i) v[i] = (bf16_t)tile[ks + i][cc];
      const int k5 = k & 31;
      const int chunk = ((c & 127) >> 5) * 2 + (k5 >> 4);
      *(bf16x8*)(&out[(size_t)((c >> 7) * 16 + (k >> 5)) * 4096 + chunk * 512 +
                      (c & 31) * 8 + ((k5 >> 3) & 1) * 256]) = v;
    }
  } else {
    int idx = blk - 192;
    const float* src; bf16_t* dst; int rt, kt2;
    if (idx < 2048) { src = x; dst = Aq; rt = idx >> 4; kt2 = idx & 15; }
    else { int i2 = idx - 2048; src = gt; dst = Akv; rt = i2 >> 4; kt2 = i2 & 15; }
    const int row = rt * 128 + (t >> 1);
    const int kb = kt2 * 32 + (t & 1) * 16;
    const float* p = src + (size_t)row * KDIM + kb;
    float4 f0 = *(const float4*)(p);
    float4 f1 = *(const float4*)(p + 4);
    float4 f2 = *(const float4*)(p + 8);
    float4 f3 = *(const float4*)(p + 12);
    bf16x8 o0 = cvt8(f0, f1), o1 = cvt8(f2, f3);
    const int chunk = ((row & 127) >> 5) * 2 + (t & 1);
    bf16_t* ob = dst + (size_t)(rt * 16 + kt2) * 4096 + chunk * 512 + (row & 31) * 8;
    *(bf16x8*)(ob) = o0;        // k-octet 0 of the 16-k segment
    *(bf16x8*)(ob + 256) = o1;  // k-octet 1
  }
}

// ---------------- projection GEMM (128x128 tile, BK=32, all-DMA) ----------------
// logical blocks 0..511: Q (Aq[16384,512]); 512..1023: KV (Akv[8192,512]).
// XCD-chunked swizzle: A'-panel sharers (consecutive logical ids) -> same XCD.
// 4 waves 2x2; wave computes 64x64 (2x2 mfma_32x32x16). One barrier per k-iter.
__global__ __launch_bounds__(256) void proj_gemm_kernel(
    const bf16_t* __restrict__ Aq, const bf16_t* __restrict__ Akv,
    const bf16_t* __restrict__ Wqt, const bf16_t* __restrict__ Wkvt,
    const float* __restrict__ bq, const float* __restrict__ bkv,
    bf16_t* __restrict__ Qf, bf16_t* __restrict__ Kf, bf16_t* __restrict__ Vf) {
  __shared__ bf16_t lds[2][8192];  // [buf][ A 4096 | W 4096 ] = 32KB
  const int raw = blockIdx.x;
  const int blk = (raw & 7) * 128 + (raw >> 3);
  int mode, bx, by;
  const bf16_t* Ab; const bf16_t* Wb; const float* bias;
  if (blk < 512) { mode = 0; bx = blk & 3; by = blk >> 2; Ab = Aq; Wb = Wqt; bias = bq; }
  else { int tt = blk - 512; mode = 1; bx = tt & 7; by = tt >> 3; Ab = Akv; Wb = Wkvt; bias = bkv; }

  const int tid = threadIdx.x;
  const int wave = tid >> 6, L = tid & 63;
  const int l5 = L & 31, hf = L >> 5;
  const int wr = wave >> 1, wc = wave & 1;
  const int rb = by * 128, cb = bx * 128;

  const bf16_t* Abase = Ab + (size_t)by * 16 * 4096 + L * 8;
  const bf16_t* Wbase = Wb + (size_t)bx * 16 * 4096 + L * 8;

  // 16 segs of 1KB per k-tile (A 8 + W 8); wave issues 4
  auto dma = [&](int buf, int kt) {
#pragma unroll
    for (int j = 0; j < 4; ++j) {
      const int s = wave * 4 + j;
      const bf16_t* g = (s < 8) ? (Abase + (size_t)kt * 4096 + s * 512)
                                : (Wbase + (size_t)kt * 4096 + (s - 8) * 512);
      gl_lds16(g, &lds[buf][(s < 8 ? s * 512 : 4096 + (s - 8) * 512) + L * 8]);
    }
  };

  dma(0, 0);
  __syncthreads();  // k-tile 0 landed

  floatx16 acc[2][2] = {};
  for (int kt = 0; kt < 16; ++kt) {
    const int cur = kt & 1;
    if (kt < 15) dma(cur ^ 1, kt + 1);  // hidden behind this iter's reads+MFMA
    bf16x8 af[2][2], wf[2][2];
#pragma unroll
    for (int rs = 0; rs < 2; ++rs)
#pragma unroll
      for (int kh = 0; kh < 2; ++kh)
        af[rs][kh] = *(const bf16x8*)(&lds[cur][((wr * 2 + rs) * 2 + kh) * 512 + L * 8]);
#pragma unroll
    for (int cs = 0; cs < 2; ++cs)
#pragma unroll
      for (int kh = 0; kh < 2; ++kh)
        wf[cs][kh] = *(const bf16x8*)(&lds[cur][4096 + ((wc * 2 + cs) * 2 + kh) * 512 + L * 8]);
    __builtin_amdgcn_s_setprio(1);
#pragma unroll
    for (int rs = 0; rs < 2; ++rs)
#pragma unroll
      for (int cs = 0; cs < 2; ++cs)
#pragma unroll
        for (int kh = 0; kh < 2; ++kh)
          acc[rs][cs] = __builtin_amdgcn_mfma_f32_32x32x16_bf16(
              af[rs][kh], wf[cs][kh], acc[rs][cs], 0, 0, 0);
    __builtin_amdgcn_s_setprio(0);
    __syncthreads();  // drains next DMA + everyone's reads of cur
  }

  // ---------------- epilogue ----------------
  // C/D layout: col=lane&31, row=(r&3)+8*(r>>2)+4*(lane>>5).
  // Q and K: stage wave's 64x64 bf16 tile in private 8KB LDS in exact Qf/Kf
  // byte order with XOR swizzle q^=((q>>9)&7)<<4, then 8 coalesced 1KB stores.
  const int colb = cb + wc * 64;  // 64-aligned wave col base
  char* stc = (char*)(&lds[0][0] + wave * 4096);  // wave-private 8KB
  const int gr0 = rb + wr * 64;

  if (mode == 0 || colb < 512) {
    bf16_t* dstT; size_t base2;
    const int hh = (colb & 511) >> 6;
    if (mode == 0) {
      const int b = gr0 >> 11, n0 = gr0 & 2047;
      base2 = 2 * ((size_t)(b * 8 + hh) * 131072 + (size_t)(n0 >> 5) * 2048);
      dstT = Qf;
    } else {
      const int b = gr0 >> 10, m0 = gr0 & 1023;
      base2 = 2 * ((size_t)(b * 8 + hh) * 65536 + (size_t)(m0 >> 5) * 2048);
      dstT = Kf;
    }
#pragma unroll
    for (int rs = 0; rs < 2; ++rs)
#pragma unroll
      for (int cs = 0; cs < 2; ++cs) {
        const int d = cs * 32 + l5;
        const float bv = bias[colb + cs * 32 + l5];
#pragma unroll
        for (int r = 0; r < 16; ++r) {
          const int nl = rs * 32 + (r & 3) + 8 * (r >> 2) + 4 * hf;
          float v = acc[rs][cs][r] + bv;
          if (mode == 0) v *= QSCALE;
          int q = ((nl >> 5) << 12) | ((d >> 3) << 9) | ((nl & 31) << 4) | ((d & 7) << 1);
          q ^= ((q >> 9) & 7) << 4;
          *(bf16_t*)(stc + q) = (bf16_t)v;
        }
      }
    // wave-private region: within-wave ds ordering handled by compiler lgkmcnt
#pragma unroll
    for (int g = 0; g < 8; ++g) {
      const int q = g * 1024 + L * 16;
      const int qs = q ^ (((q >> 9) & 7) << 4);
      bf16x8 vv = *(const bf16x8*)(stc + qs);
      *(bf16x8*)((char*)dstT + base2 + q) = vv;
    }
  } else {  // V waves: direct b64 frag stores
#pragma unroll
    for (int rs = 0; rs < 2; ++rs)
#pragma unroll
      for (int cs = 0; cs < 2; ++cs) {
        const int col = colb + cs * 32 + l5;
        const float bv = bias[col];
        const int grb = gr0 + rs * 32;
        const int cc = col - 512;
        const int hh = cc >> 6, d = cc & 63;
        const int dof = (d >> 5) * 1024 + (d & 31) * 8;
#pragma unroll
        for (int rq = 0; rq < 4; ++rq) {
          int gr = grb + 8 * rq + 4 * hf;
          int b = gr >> 10, m = gr & 1023;
          bf16x4 pk;
          pk[0] = (bf16_t)(acc[rs][cs][rq * 4 + 0] + bv);
          pk[1] = (bf16_t)(acc[rs][cs][rq * 4 + 1] + bv);
          pk[2] = (bf16_t)(acc[rs][cs][rq * 4 + 2] + bv);
          pk[3] = (bf16_t)(acc[rs][cs][rq * 4 + 3] + bv);
          *(bf16x4*)(&Vf[(size_t)(b * 8 + hh) * 65536 + (m >> 5) * 2048 + dof +
                         ((m >> 4) & 1) * 512 + ((m >> 3) & 1) * 256 + (m & 7)]) = pk;
        }
      }
  }
}

// ---------------- flash attention (ring-4 subtile pipeline, XCD-owned bh) ---------
// 1-D grid of 1024 blocks. xcd = blk&7 (HW round-robin assumption: block i ->
// XCD i%8). Each XCD owns 8 bh values; all 16 n-blocks of a bh land on one
// XCD so its K/V (256KB) is fetched from HBM once and served from that L2.
__global__ __launch_bounds__(256, 4) void flash_attn_kernel(
    const bf16_t* __restrict__ Qf, const bf16_t* __restrict__ Kf,
    const bf16_t* __restrict__ Vf, float* __restrict__ out) {
  __shared__ bf16_t kv[4][4096];  // 32KB total
  const int tid = threadIdx.x;
  const int wave = tid >> 6, L = tid & 63;
  const int l5 = L & 31, hf = L >> 5;
  const int blk = blockIdx.x;
  const int xcd = blk & 7, slot = blk >> 3;       // slot 0..127
  const int bh = xcd * 8 + (slot >> 4);           // 8 bh per XCD
  const int nbx = slot & 15;
  const int b = bh >> 3, hh = bh & 7;
  const int nb = nbx * 128 + wave * 32;

  const bf16_t* Qp = Qf + (size_t)bh * 131072 + (nb >> 5) * 2048 + L * 8;
  const bf16_t* Kb = Kf + (size_t)bh * 65536 + L * 8;
  const bf16_t* Vb = Vf + (size_t)bh * 65536 + L * 8;

  bf16x8 qf[4];
#pragma unroll
  for (int kc = 0; kc < 4; ++kc) qf[kc] = *(const bf16x8*)(Qp + kc * 512);

  bf16x8 ones;
#pragma unroll
  for (int i = 0; i < 8; ++i) ones[i] = (bf16_t)1.0f;

  floatx16 o0 = {}, o1 = {}, lacc = {};

  auto dma = [&](int buf, int s) {
#pragma unroll
    for (int j = 0; j < 2; ++j) {
      const int q = wave * 2 + j;
      const bf16_t* g = (q < 4) ? (Kb + (size_t)s * 2048 + q * 512)
                                : (Vb + (size_t)s * 2048 + (q - 4) * 512);
      gl_lds16(g, &kv[buf][(q < 4 ? q * 512 : 2048 + (q - 4) * 512) + L * 8]);
    }
  };

  auto subtile = [&](int s) {
    const bf16_t* kb = &kv[s & 3][L * 8];
    const bf16_t* vb = &kv[s & 3][2048 + L * 8];
    bf16x8 kf4[4];
#pragma unroll
    for (int kc = 0; kc < 4; ++kc) kf4[kc] = *(const bf16x8*)(kb + kc * 512);
    floatx16 sa = {};
    __builtin_amdgcn_s_setprio(1);
#pragma unroll
    for (int kc = 0; kc < 4; ++kc)
      sa = __builtin_amdgcn_mfma_f32_32x32x16_bf16(kf4[kc], qf[kc], sa, 0, 0, 0);
    __builtin_amdgcn_s_setprio(0);
    bf16x8 vf4[4];
#pragma unroll
    for (int j = 0; j < 4; ++j) vf4[j] = *(const bf16x8*)(vb + j * 512);
    unsigned w[8];
#pragma unroll
    for (int i = 0; i < 8; ++i) {
      float pa = fexp2(sa[2 * i]), pb = fexp2(sa[2 * i + 1]);
      w[i] = pack2(pa, pb);
    }
    uintx4 fw0, fw1;
#if __has_builtin(__builtin_amdgcn_permlane32_swap)
    {
      uintx2 r0 = __builtin_amdgcn_permlane32_swap(w[0], w[2], false, false);
      uintx2 r1 = __builtin_amdgcn_permlane32_swap(w[1], w[3], false, false);
      uintx2 r2 = __builtin_amdgcn_permlane32_swap(w[4], w[6], false, false);
      uintx2 r3 = __builtin_amdgcn_permlane32_swap(w[5], w[7], false, false);
      fw0.x = r0[0]; fw0.z = r0[1];
      fw0.y = r1[0]; fw0.w = r1[1];
      fw1.x = r2[0]; fw1.z = r2[1];
      fw1.y = r3[0]; fw1.w = r3[1];
    }
#else
    {
      unsigned sw[8];
#pragma unroll
      for (int i = 0; i < 8; ++i) sw[i] = __shfl_xor(w[i], 32);
      fw0.x = hf ? sw[2] : w[0]; fw0.y = hf ? sw[3] : w[1];
      fw0.z = hf ? w[2] : sw[0]; fw0.w = hf ? w[3] : sw[1];
      fw1.x = hf ? sw[6] : w[4]; fw1.y = hf ? sw[7] : w[5];
      fw1.z = hf ? w[6] : sw[4]; fw1.w = hf ? w[7] : sw[5];
    }
#endif
    bf16x8 pf0 = __builtin_bit_cast(bf16x8, fw0);
    bf16x8 pf1 = __builtin_bit_cast(bf16x8, fw1);
    __builtin_amdgcn_s_setprio(1);
    lacc = __builtin_amdgcn_mfma_f32_32x32x16_bf16(ones, pf0, lacc, 0, 0, 0);
    lacc = __builtin_amdgcn_mfma_f32_32x32x16_bf16(ones, pf1, lacc, 0, 0, 0);
    o0 = __builtin_amdgcn_mfma_f32_32x32x16_bf16(vf4[0], pf0, o0, 0, 0, 0);
    o0 = __builtin_amdgcn_mfma_f32_32x32x16_bf16(vf4[1], pf1, o0, 0, 0, 0);
    o1 = __builtin_amdgcn_mfma_f32_32x32x16_bf16(vf4[2], pf0, o1, 0, 0, 0);
    o1 = __builtin_amdgcn_mfma_f32_32x32x16_bf16(vf4[3], pf1, o1, 0, 0, 0);
    __builtin_amdgcn_s_setprio(0);
  };

  dma(0, 0);
  dma(1, 1);
  dma(2, 2);  // 6 loads/wave in flight

  for (int s = 0; s < 30; ++s) {
    WAITVM(4);  // subtile s landed; s+1, s+2 stay in flight
    BAR();
    if (s <= 28) dma((s + 3) & 3, s + 3);
    subtile(s);
  }
  WAITVM(2);
  BAR();
  subtile(30);
  WAITVM(0);
  BAR();
  subtile(31);

  __syncthreads();  // all compute done before LDS is reused for output staging

  const float inv = 1.0f / lacc[0];

  float* lob = (float*)(&kv[0][0]) + wave * (32 * 36);
  const size_t orow = (size_t)b * 2048 + nb;
#pragma unroll
  for (int pass = 0; pass < 2; ++pass) {
    const floatx16& oo = pass ? o1 : o0;
#pragma unroll
    for (int i = 0; i < 8; ++i) {
      const int d = 2 * (i & 1) + 8 * (i >> 1) + 4 * hf;
      float2 a;
      a.x = oo[2 * i] * inv; a.y = oo[2 * i + 1] * inv;
      *(float2*)(&lob[l5 * 36 + d]) = a;
    }
#pragma unroll
    for (int j = 0; j < 4; ++j) {
      int chunk = j * 64 + L;
      int n = chunk >> 3, c = chunk & 7;
      float4 v = *(const float4*)(&lob[n * 36 + c * 4]);
      *(float4*)(&out[(orow + n) * 512 + hh * 64 + pass * 32 + c * 4]) = v;
    }
  }
}

extern "C" void kernel_launch(void* const* d_in, const int* in_sizes, int n_in,
                              void* d_out, int out_size, void* d_ws, size_t ws_size,
                              hipStream_t stream) {
  (void)in_sizes; (void)n_in; (void)out_size; (void)ws_size;
  const float* x   = (const float*)d_in[0];
  const float* gt  = (const float*)d_in[1];
  const float* Wq  = (const float*)d_in[2];
  const float* bq  = (const float*)d_in[3];
  const float* Wkv = (const float*)d_in[4];
  const float* bkv = (const float*)d_in[5];
  float* out = (float*)d_out;

  // ws: weights + Q/K/V frag buffers
  bf16_t* Wqt  = (bf16_t*)d_ws;
  bf16_t* Wkvt = Wqt + (size_t)512 * 512;
  bf16_t* Qf   = Wkvt + (size_t)1024 * 512;
  bf16_t* Kf   = Qf + (size_t)64 * 2048 * 64;
  bf16_t* Vf   = Kf + (size_t)64 * 1024 * 64;
  // A' bf16 scratch (24 MB) lives in d_out (33.5 MB); consumed by GEMM,
  // then flash overwrites d_out with the final result.
  bf16_t* Aq   = (bf16_t*)d_out;
  bf16_t* Akv  = Aq + (size_t)16384 * 512;

  prep_kernel<<<3264, 256, 0, stream>>>(Wq, Wkv, x, gt, Wqt, Wkvt, Aq, Akv);
  proj_gemm_kernel<<<1024, 256, 0, stream>>>(Aq, Akv, Wqt, Wkvt, bq, bkv, Qf, Kf, Vf);
  flash_attn_kernel<<<1024, 256, 0, stream>>>(Qf, Kf, Vf, out);
}